// Round 11
// baseline (14.290 us; speedup 1.0000x reference)
//
#include <hip/hip_runtime.h>

// GraphVolterraLayer: N_S=64, N_T=32, N_EFF=2048, K_T1=K_T2=8, BATCH=16.
// One kernel, grid 512 = (b, iT), 256 threads (4 waves), 4 barriers,
// ~67 KB LDS -> 2 blocks/CU (independent barrier chains overlap).
//
//  P0: stage S^T/UG^T bf16 hi/lo (swz), UG hi (swz), UPT f32; raw weights
//  P1: T1 = UG^T S (MFMA 3-term hi/lo, 2 tiles/wave) + weight fold w' = wR UPT^T
//  P3a: Gm/A/Q = T1 x w' (fp32 VALU); Gm,A -> bf16 hi/lo packs; wv reduce
//  P3b: E = HS .* (A Gm^T) via packed MFMA ([Ah|Ah|Al|0]x[Gh|Gl|Gh|0]);
//       E -> bf16 XOR-swz (same-wave rows); z1 partials = UG^T wv (fp32)
//  P4:  (no barrier before: E rows are wave-local) F = E UG^T (MFMA hi-only);
//       z2[iS] = sum_kS UG[iS,kS] F[kS,iS]
//  P5: out = h0 + z1 + z2
// mfma: D[row][col] = sum_k A[row][k]*B[col][k]; D-layout col=l&15,
// row=4*(l>>4)+reg (m89; validated on-problem r6-r10).

typedef short  bf16x8 __attribute__((ext_vector_type(8)));
typedef float  f32x4  __attribute__((ext_vector_type(4)));
typedef unsigned short u16;

static __device__ __forceinline__ u16 f2bf(float f) {
  unsigned u = __float_as_uint(f);
  u = (u + 0x7fff + ((u >> 16) & 1)) >> 16;    // RNE
  return (u16)u;
}
static __device__ __forceinline__ float bf2f(u16 h) {
  return __uint_as_float(((unsigned)h) << 16);
}
static __device__ __forceinline__ float dot4(f32x4 a, f32x4 b) {
  return a.x * b.x + a.y * b.y + a.z * b.z + a.w * b.w;
}

__global__ __launch_bounds__(256) void volterra_one(
    const float* __restrict__ s, const float* __restrict__ UG,
    const float* __restrict__ UPT, const float* __restrict__ h0,
    const float* __restrict__ h1c, const float* __restrict__ HS,
    const float* __restrict__ Hc, float* __restrict__ out)
{
  const int b  = blockIdx.x >> 5;
  const int iT = blockIdx.x & 31;
  const int t  = threadIdx.x;
  const int w  = t >> 6;             // wave 0..3
  const int l  = t & 63;
  const int r  = l & 15;
  const int g  = l >> 4;

  __shared__ __align__(16) u16   sSTh[2048], sSTl[2048];   // S^T [32][64] swz
  __shared__ __align__(16) u16   sUGTh[4096], sUGTl[4096]; // UG^T [64][64] swz
  __shared__ __align__(16) u16   sUGh[4096];               // UG [64][64] swz hi
  __shared__ __align__(16) float sUPT[32][36];
  __shared__ __align__(16) float wGmR[288], wAR[288], wQR[288];
  __shared__ __align__(16) float wGmP[288], wAP[288], wQP[288];
  __shared__ __align__(16) float sT1[64][36];
  __shared__ __align__(16) u16   sGh[64][8], sGl[64][8];   // Gm hi/lo packs
  __shared__ __align__(16) u16   sAh[64][8], sAl[64][8];   // A  hi/lo packs
  __shared__ __align__(16) u16   szero16[8];
  __shared__ __align__(16) u16   sE[4096];
  __shared__ float wv[64];
  __shared__ float zp1[4][64], zpart[4][64];

  // ---- P0: stage ----
  #pragma unroll
  for (int it = 0; it < 2; ++it) {   // S^T bf16 hi/lo, chunk-XOR swizzled
    const int o4 = t + it * 256;
    const f32x4 v = ((const f32x4*)(s + b * 2048))[o4];
    const int rr = o4 >> 3, c0 = (o4 & 7) * 4;
    const float arr[4] = {v.x, v.y, v.z, v.w};
    #pragma unroll
    for (int i = 0; i < 4; ++i) {
      const int c = c0 + i;
      const u16 hi = f2bf(arr[i]);
      const int ad = c * 64 + (((rr >> 3) ^ (c & 7)) << 3) + (rr & 7);
      sSTh[ad] = hi;
      sSTl[ad] = f2bf(arr[i] - bf2f(hi));
    }
  }
  #pragma unroll
  for (int it = 0; it < 4; ++it) {   // UG: row-major hi + transposed hi/lo
    const int o4 = t + it * 256;
    const int rr = o4 >> 4, c0 = (o4 & 15) * 4;
    const f32x4 v = ((const f32x4*)UG)[o4];
    const float arr[4] = {v.x, v.y, v.z, v.w};
    short4 h4;
    h4.x = (short)f2bf(v.x); h4.y = (short)f2bf(v.y);
    h4.z = (short)f2bf(v.z); h4.w = (short)f2bf(v.w);
    *(short4*)&sUGh[rr * 64 + (c0 ^ ((rr & 7) << 3))] = h4;
    #pragma unroll
    for (int i = 0; i < 4; ++i) {
      const int c = c0 + i;
      const u16 hi = f2bf(arr[i]);
      const int ad = c * 64 + (((rr >> 3) ^ (c & 7)) << 3) + (rr & 7);
      sUGTh[ad] = hi;
      sUGTl[ad] = f2bf(arr[i] - bf2f(hi));
    }
  }
  {                                  // UPT fp32 (256 f32x4 = all threads)
    *(f32x4*)&sUPT[t >> 3][(t & 7) * 4] = ((const f32x4*)UPT)[t];
  }
  if (t < 8) szero16[t] = 0;
  {                                  // raw weights (global reads only)
    const int p = t >> 5, k = t & 31;
    const float m1 = UPT[iT * 32 + k];
    const float m3 = UPT[k * 32 + iT];
    const float m2 = UPT[k * 32 + p];
    float uh = 0.f;
    #pragma unroll
    for (int q = 0; q < 8; ++q) uh += UPT[k * 32 + q] * Hc[q * 8 + p];
    wGmR[p * 36 + k] = m1 * m2;
    wAR [p * 36 + k] = m1 * uh;
    wQR [p * 36 + k] = m3 * m2;
  }
  __syncthreads();

  // ---- P1: T1 = UG^T S (2 tiles/wave) + weight fold ----
  #pragma unroll
  for (int ct = 0; ct < 2; ++ct) {
    const int rowA = 16 * w + r, rowB = ct * 16 + r;
    f32x4 acc = {0.f, 0.f, 0.f, 0.f};
    #pragma unroll
    for (int kc = 0; kc < 2; ++kc) {
      const int ch = kc * 4 + g;
      const int oa = rowA * 64 + ((ch ^ (rowA & 7)) << 3);
      const int ob = rowB * 64 + ((ch ^ (rowB & 7)) << 3);
      const bf16x8 Ah = *(const bf16x8*)&sUGTh[oa];
      const bf16x8 Al = *(const bf16x8*)&sUGTl[oa];
      const bf16x8 Bh = *(const bf16x8*)&sSTh[ob];
      const bf16x8 Bl = *(const bf16x8*)&sSTl[ob];
      acc = __builtin_amdgcn_mfma_f32_16x16x32_bf16(Ah, Bh, acc, 0, 0, 0);
      acc = __builtin_amdgcn_mfma_f32_16x16x32_bf16(Ah, Bl, acc, 0, 0, 0);
      acc = __builtin_amdgcn_mfma_f32_16x16x32_bf16(Al, Bh, acc, 0, 0, 0);
    }
    #pragma unroll
    for (int reg = 0; reg < 4; ++reg)
      sT1[16 * w + 4 * g + reg][ct * 16 + r] = acc[reg];
  }
  {  // w'[p][j] = sum_k UPT[j,k] * wR[p][k]   (VALU, overlaps MFMA)
    const int p = t >> 5, j = t & 31;
    float aG = 0.f, aA = 0.f, aQ = 0.f;
    #pragma unroll
    for (int k4 = 0; k4 < 8; ++k4) {
      const f32x4 u  = *(const f32x4*)&sUPT[j][k4 * 4];
      const f32x4 w1 = *(const f32x4*)&wGmR[p * 36 + k4 * 4];
      const f32x4 w2 = *(const f32x4*)&wAR [p * 36 + k4 * 4];
      const f32x4 w3 = *(const f32x4*)&wQR [p * 36 + k4 * 4];
      aG += dot4(u, w1); aA += dot4(u, w2); aQ += dot4(u, w3);
    }
    wGmP[p * 36 + j] = aG;
    wAP [p * 36 + j] = aA;
    wQP [p * 36 + j] = aQ;
  }
  __syncthreads();

  // ---- P3a: Gm/A/Q = T1 x w' (fp32) -> bf16 hi/lo packs + wv reduce ----
  {
    const int kSa = t >> 3, p = t & 7;
    float g0 = 0.f, g1v = 0.f, a0 = 0.f, a1v = 0.f, q0 = 0.f, q1v = 0.f;
    #pragma unroll
    for (int c4 = 0; c4 < 8; ++c4) {
      const f32x4 w1 = *(const f32x4*)&wGmP[p * 36 + c4 * 4];
      const f32x4 w2 = *(const f32x4*)&wAP [p * 36 + c4 * 4];
      const f32x4 w3 = *(const f32x4*)&wQP [p * 36 + c4 * 4];
      const f32x4 x0 = *(const f32x4*)&sT1[kSa][c4 * 4];
      const f32x4 x1 = *(const f32x4*)&sT1[kSa + 32][c4 * 4];
      g0  += dot4(x0, w1); a0  += dot4(x0, w2); q0  += dot4(x0, w3);
      g1v += dot4(x1, w1); a1v += dot4(x1, w2); q1v += dot4(x1, w3);
    }
    const u16 gh0 = f2bf(g0);
    sGh[kSa][p] = gh0;       sGl[kSa][p] = f2bf(g0 - bf2f(gh0));
    const u16 gh1 = f2bf(g1v);
    sGh[kSa + 32][p] = gh1;  sGl[kSa + 32][p] = f2bf(g1v - bf2f(gh1));
    const u16 ah0 = f2bf(a0);
    sAh[kSa][p] = ah0;       sAl[kSa][p] = f2bf(a0 - bf2f(ah0));
    const u16 ah1 = f2bf(a1v);
    sAh[kSa + 32][p] = ah1;  sAl[kSa + 32][p] = f2bf(a1v - bf2f(ah1));
    float wv0 = h1c[kSa * 8 + p] * q0;
    float wv1 = h1c[(kSa + 32) * 8 + p] * q1v;
    wv0 += __shfl_xor(wv0, 1); wv0 += __shfl_xor(wv0, 2); wv0 += __shfl_xor(wv0, 4);
    wv1 += __shfl_xor(wv1, 1); wv1 += __shfl_xor(wv1, 2); wv1 += __shfl_xor(wv1, 4);
    if (p == 0) { wv[kSa] = wv0; wv[kSa + 32] = wv1; }
  }
  __syncthreads();

  // ---- P3b: E = HS .* (A Gm^T) via packed MFMA; z1 partials ----
  {
    // A-frag k-slots [Ah|Ah|Al|0], B-frag [Gh|Gl|Gh|0] -> AhGh+AhGl+AlGh
    const int rowA = 16 * w + r;
    const u16* ap = (g < 2)  ? &sAh[rowA][0]
                  : (g == 2) ? &sAl[rowA][0] : szero16;
    const bf16x8 af = *(const bf16x8*)ap;
    #pragma unroll
    for (int cb = 0; cb < 4; ++cb) {
      const int rowB = 16 * cb + r;
      const u16* bp = (g == 0) ? &sGh[rowB][0]
                    : (g == 1) ? &sGl[rowB][0]
                    : (g == 2) ? &sGh[rowB][0] : szero16;
      const bf16x8 bf = *(const bf16x8*)bp;
      f32x4 acc = {0.f, 0.f, 0.f, 0.f};
      acc = __builtin_amdgcn_mfma_f32_16x16x32_bf16(af, bf, acc, 0, 0, 0);
      #pragma unroll
      for (int reg = 0; reg < 4; ++reg) {
        const int row = 16 * w + 4 * g + reg;       // wave-local rows
        const int col = 16 * cb + r;
        const float e = acc[reg] * HS[row * 64 + col];   // L2-hot global
        sE[row * 64 + (col ^ ((row & 7) << 3))] = f2bf(e);
      }
    }
    const float wvl = wv[l];
    float part = 0.f;
    #pragma unroll
    for (int j = 0; j < 16; ++j) {
      const int kk = 16 * w + j;
      part += __shfl(wvl, kk) * UG[kk * 64 + l];         // exact fp32, L2-hot
    }
    zp1[w][l] = part;
  }
  // NO barrier: P4's E rows (16w..16w+15) are written by this same wave;
  // wave-local LDS write->read ordering is enforced by lgkmcnt.

  // ---- P4: F = E UG^T (MFMA hi-only); fuse z2 ----
  {
    f32x4 acc[4];
    #pragma unroll
    for (int nt = 0; nt < 4; ++nt) acc[nt] = (f32x4){0.f, 0.f, 0.f, 0.f};
    #pragma unroll
    for (int ks = 0; ks < 2; ++ks) {
      const int kcol = g * 8 + ks * 32;
      const int rowA = 16 * w + r;
      const bf16x8 ah = *(const bf16x8*)&sE[rowA * 64 + (kcol ^ ((rowA & 7) << 3))];
      #pragma unroll
      for (int nt = 0; nt < 4; ++nt) {
        const int rowB = 16 * nt + r;
        const bf16x8 bh = *(const bf16x8*)&sUGh[rowB * 64 + (kcol ^ ((rowB & 7) << 3))];
        acc[nt] = __builtin_amdgcn_mfma_f32_16x16x32_bf16(ah, bh, acc[nt], 0, 0, 0);
      }
    }
    #pragma unroll
    for (int nt = 0; nt < 4; ++nt) {
      float zp = 0.f;
      #pragma unroll
      for (int reg = 0; reg < 4; ++reg) {
        const int kS = 16 * w + 4 * g + reg;
        const int iS = 16 * nt + r;
        zp += bf2f(sUGh[iS * 64 + (kS ^ ((iS & 7) << 3))]) * acc[nt][reg];
      }
      zp += __shfl_xor(zp, 16);
      zp += __shfl_xor(zp, 32);
      if (g == 0) zpart[w][16 * nt + r] = zp;
    }
  }
  __syncthreads();

  // ---- P5: combine + write ----
  if (t < 64) {
    const float z2 = zpart[0][t] + zpart[1][t] + zpart[2][t] + zpart[3][t];
    const float z1 = zp1[0][t] + zp1[1][t] + zp1[2][t] + zp1[3][t];
    const int col = t * 32 + iT;
    out[b * 2048 + col] = h0[col] + z1 + z2;
  }
}

extern "C" void kernel_launch(void* const* d_in, const int* in_sizes, int n_in,
                              void* d_out, int out_size, void* d_ws, size_t ws_size,
                              hipStream_t stream) {
  const float* s   = (const float*)d_in[0];  // (16,2048)
  const float* UG  = (const float*)d_in[1];  // (64,64)
  const float* UPT = (const float*)d_in[2];  // (32,32)
  const float* h0  = (const float*)d_in[3];  // (2048,)
  const float* h1c = (const float*)d_in[4];  // (64,8)
  const float* HS  = (const float*)d_in[5];  // (64,64)
  const float* Hc  = (const float*)d_in[6];  // (8,8)
  float* out = (float*)d_out;

  volterra_one<<<512, 256, 0, stream>>>(s, UG, UPT, h0, h1c, HS, Hc, out);
}

// Round 12
// 12.971 us; speedup vs baseline: 1.1017x; 1.1017x over previous
//
#include <hip/hip_runtime.h>

// GraphVolterraLayer: N_S=64, N_T=32, N_EFF=2048, K_T1=K_T2=8, BATCH=16.
// One kernel, grid 256 = (b, iT-pair), 512 threads (8 waves), 4 barriers.
//
//  P0: stage S^T/UG^T bf16 hi/lo (swz), UG hi (swz), UPT f32; raw side weights
//  P1: T1 = UG^T S (MFMA 3-term hi/lo) -> T1 bf16 hi/lo LDS;
//      weight fold w' = wR UPT^T (VALU, overlaps) -> bf16 hi/lo packs
//      [GmA pack rows 0-7 = wGm', 8-15 = wA'; Q pack rows 0-7 = wQ', 8-15 = 0]
//  P3a: {Gm|A} = T1 x GmA-pack, Q = T1 x Q-pack via MFMA (3-term, K=32 exact);
//       Gm,A -> bf16 hi/lo packs [64][8]; wv = rowreduce(h1c .* Q) via shfl
//  P3b: E = HS .* (A Gm^T) via packed MFMA ([Ah|Ah|Al|0]x[Gh|Gl|Gh|0]);
//       E -> bf16 XOR-swz (wave-local rows); z1 partials = UG^T wv (fp32)
//  P4:  (no barrier: E rows wave-local) F = E UG^T (MFMA hi-only); fuse z2
//  P5: out = h0 + z1 + z2
// mfma: D[row][col] = sum_k A[row][k]*B[col][k]; A/B: lane row=l&15,
// k-chunk=(l>>4)*8; D: col=l&15, row=4*(l>>4)+reg (m89; validated r6-r11).

typedef short  bf16x8 __attribute__((ext_vector_type(8)));
typedef float  f32x4  __attribute__((ext_vector_type(4)));
typedef unsigned short u16;

static __device__ __forceinline__ u16 f2bf(float f) {
  unsigned u = __float_as_uint(f);
  u = (u + 0x7fff + ((u >> 16) & 1)) >> 16;    // RNE
  return (u16)u;
}
static __device__ __forceinline__ float bf2f(u16 h) {
  return __uint_as_float(((unsigned)h) << 16);
}
static __device__ __forceinline__ float dot4(f32x4 a, f32x4 b) {
  return a.x * b.x + a.y * b.y + a.z * b.z + a.w * b.w;
}
// [N][32]-u16 chunk-swizzled addr (8-u16 chunks; <=2-way bank alias)
static __device__ __forceinline__ int padr(int row, int col) {
  return row * 32 +
         ((((col >> 3) ^ (row & 3) ^ (((row >> 2) & 1) << 1)) & 3) << 3) +
         (col & 7);
}

__global__ __launch_bounds__(512) void volterra_one(
    const float* __restrict__ s, const float* __restrict__ UG,
    const float* __restrict__ UPT, const float* __restrict__ h0,
    const float* __restrict__ h1c, const float* __restrict__ HS,
    const float* __restrict__ Hc, float* __restrict__ out)
{
  const int b   = blockIdx.x >> 4;
  const int iT0 = (blockIdx.x & 15) << 1;
  const int t   = threadIdx.x;
  const int w   = t >> 6;            // wave 0..7
  const int l   = t & 63;
  const int r   = l & 15;
  const int g   = l >> 4;

  __shared__ __align__(16) u16   sSTh[2048], sSTl[2048];   // S^T [32][64] swz
  __shared__ __align__(16) u16   sUGTh[4096], sUGTl[4096]; // UG^T [64][64] swz
  __shared__ __align__(16) u16   sUGh[4096];               // UG [64][64] swz hi
  __shared__ __align__(16) float sUPT[32][36];
  __shared__ __align__(16) float wGmR[2][288], wAR[2][288], wQR[2][288];
  __shared__ __align__(16) u16   sT1h[2048], sT1l[2048];   // T1 [64][32] swz
  __shared__ __align__(16) u16   sWGAh[2][512], sWGAl[2][512]; // {Gm|A} w-packs
  __shared__ __align__(16) u16   sWQh[2][512], sWQl[2][512];   // Q w-pack
  __shared__ __align__(16) u16   sGh[2][64][8], sGl[2][64][8]; // Gm hi/lo
  __shared__ __align__(16) u16   sAh[2][64][8], sAl[2][64][8]; // A  hi/lo
  __shared__ __align__(16) u16   szero16[8];
  __shared__ __align__(16) u16   sE[2][4096];
  __shared__ float wv[2][64];
  __shared__ float zp1[2][4][64], zpart[2][4][64];

  // ---- P0: stage ----
  {  // S^T bf16 hi/lo, chunk-XOR swizzled
    const f32x4 v = ((const f32x4*)(s + b * 2048))[t];
    const int rr = t >> 3, c0 = (t & 7) * 4;
    const float arr[4] = {v.x, v.y, v.z, v.w};
    #pragma unroll
    for (int i = 0; i < 4; ++i) {
      const int c = c0 + i;
      const u16 hi = f2bf(arr[i]);
      const int ad = c * 64 + (((rr >> 3) ^ (c & 7)) << 3) + (rr & 7);
      sSTh[ad] = hi;
      sSTl[ad] = f2bf(arr[i] - bf2f(hi));
    }
  }
  #pragma unroll
  for (int it = 0; it < 2; ++it) {   // UG: row-major hi + transposed hi/lo
    const int o4 = t + it * 512;
    const int rr = o4 >> 4, c0 = (o4 & 15) * 4;
    const f32x4 v = ((const f32x4*)UG)[o4];
    const float arr[4] = {v.x, v.y, v.z, v.w};
    short4 h4;
    h4.x = (short)f2bf(v.x); h4.y = (short)f2bf(v.y);
    h4.z = (short)f2bf(v.z); h4.w = (short)f2bf(v.w);
    *(short4*)&sUGh[rr * 64 + (c0 ^ ((rr & 7) << 3))] = h4;
    #pragma unroll
    for (int i = 0; i < 4; ++i) {
      const int c = c0 + i;
      const u16 hi = f2bf(arr[i]);
      const int ad = c * 64 + (((rr >> 3) ^ (c & 7)) << 3) + (rr & 7);
      sUGTh[ad] = hi;
      sUGTl[ad] = f2bf(arr[i] - bf2f(hi));
    }
  }
  if (t < 256) {                     // UPT fp32
    *(f32x4*)&sUPT[t >> 3][(t & 7) * 4] = ((const f32x4*)UPT)[t];
  }
  if (t < 8) szero16[t] = 0;
  {                                  // raw per-side weights (global reads only)
    const int side = t >> 8, p = (t >> 5) & 7, k = t & 31;
    const int iTs = iT0 + side;
    const float m1 = UPT[iTs * 32 + k];
    const float m3 = UPT[k * 32 + iTs];
    const float m2 = UPT[k * 32 + p];
    float uh = 0.f;
    #pragma unroll
    for (int q = 0; q < 8; ++q) uh += UPT[k * 32 + q] * Hc[q * 8 + p];
    wGmR[side][p * 36 + k] = m1 * m2;
    wAR [side][p * 36 + k] = m1 * uh;
    wQR [side][p * 36 + k] = m3 * m2;
  }
  __syncthreads();

  // ---- P1: T1 = UG^T S (8 wave-tiles) -> bf16 hi/lo; weight fold -> packs ----
  {
    const int band = w >> 1, ct = w & 1;
    const int rowA = 16 * band + r, rowB = ct * 16 + r;
    f32x4 acc = {0.f, 0.f, 0.f, 0.f};
    #pragma unroll
    for (int kc = 0; kc < 2; ++kc) {
      const int ch = kc * 4 + g;
      const int oa = rowA * 64 + ((ch ^ (rowA & 7)) << 3);
      const int ob = rowB * 64 + ((ch ^ (rowB & 7)) << 3);
      const bf16x8 Ah = *(const bf16x8*)&sUGTh[oa];
      const bf16x8 Al = *(const bf16x8*)&sUGTl[oa];
      const bf16x8 Bh = *(const bf16x8*)&sSTh[ob];
      const bf16x8 Bl = *(const bf16x8*)&sSTl[ob];
      acc = __builtin_amdgcn_mfma_f32_16x16x32_bf16(Ah, Bh, acc, 0, 0, 0);
      acc = __builtin_amdgcn_mfma_f32_16x16x32_bf16(Ah, Bl, acc, 0, 0, 0);
      acc = __builtin_amdgcn_mfma_f32_16x16x32_bf16(Al, Bh, acc, 0, 0, 0);
    }
    #pragma unroll
    for (int reg = 0; reg < 4; ++reg) {
      const int row = 16 * band + 4 * g + reg;
      const int ad = padr(row, ct * 16 + r);
      const u16 hi = f2bf(acc[reg]);
      sT1h[ad] = hi;
      sT1l[ad] = f2bf(acc[reg] - bf2f(hi));
    }
  }
  {  // w'[p][j] = sum_k UPT[j,k] * wR[p][k]  (VALU, overlaps MFMA) -> packs
    const int side = t >> 8, p = (t >> 5) & 7, j = t & 31;
    float aG = 0.f, aA = 0.f, aQ = 0.f;
    #pragma unroll
    for (int k4 = 0; k4 < 8; ++k4) {
      const f32x4 u  = *(const f32x4*)&sUPT[j][k4 * 4];
      const f32x4 w1 = *(const f32x4*)&wGmR[side][p * 36 + k4 * 4];
      const f32x4 w2 = *(const f32x4*)&wAR [side][p * 36 + k4 * 4];
      const f32x4 w3 = *(const f32x4*)&wQR [side][p * 36 + k4 * 4];
      aG += dot4(u, w1); aA += dot4(u, w2); aQ += dot4(u, w3);
    }
    const int adG = padr(p, j), adA = padr(8 + p, j);
    u16 h;
    h = f2bf(aG); sWGAh[side][adG] = h; sWGAl[side][adG] = f2bf(aG - bf2f(h));
    h = f2bf(aA); sWGAh[side][adA] = h; sWGAl[side][adA] = f2bf(aA - bf2f(h));
    h = f2bf(aQ); sWQh[side][adG]  = h; sWQl[side][adG]  = f2bf(aQ - bf2f(h));
    sWQh[side][adA] = 0; sWQl[side][adA] = 0;
  }
  __syncthreads();

  // ---- P3a: {Gm|A} and Q via MFMA (K=32 exact); packs + wv reduce ----
  {
    const int side = t >> 8, sub = (t >> 6) & 3;
    const int rowA = 16 * sub + r;
    const int oa = padr(rowA, g * 8);
    const bf16x8 Ah = *(const bf16x8*)&sT1h[oa];
    const bf16x8 Al = *(const bf16x8*)&sT1l[oa];
    const int ob = padr(r, g * 8);
    const bf16x8 GAh = *(const bf16x8*)&sWGAh[side][ob];
    const bf16x8 GAl = *(const bf16x8*)&sWGAl[side][ob];
    const bf16x8 Qh  = *(const bf16x8*)&sWQh[side][ob];
    const bf16x8 Ql  = *(const bf16x8*)&sWQl[side][ob];
    f32x4 accGA = {0.f, 0.f, 0.f, 0.f}, accQ = {0.f, 0.f, 0.f, 0.f};
    accGA = __builtin_amdgcn_mfma_f32_16x16x32_bf16(Ah, GAh, accGA, 0, 0, 0);
    accGA = __builtin_amdgcn_mfma_f32_16x16x32_bf16(Ah, GAl, accGA, 0, 0, 0);
    accGA = __builtin_amdgcn_mfma_f32_16x16x32_bf16(Al, GAh, accGA, 0, 0, 0);
    accQ  = __builtin_amdgcn_mfma_f32_16x16x32_bf16(Ah, Qh,  accQ,  0, 0, 0);
    accQ  = __builtin_amdgcn_mfma_f32_16x16x32_bf16(Ah, Ql,  accQ,  0, 0, 0);
    accQ  = __builtin_amdgcn_mfma_f32_16x16x32_bf16(Al, Qh,  accQ,  0, 0, 0);
    #pragma unroll
    for (int reg = 0; reg < 4; ++reg) {
      const int row = 16 * sub + 4 * g + reg;
      const float v = accGA[reg];
      const u16 h = f2bf(v);
      const u16 lo = f2bf(v - bf2f(h));
      if (r < 8) { sGh[side][row][r] = h;     sGl[side][row][r] = lo; }
      else       { sAh[side][row][r - 8] = h; sAl[side][row][r - 8] = lo; }
      float pr = (r < 8) ? h1c[row * 8 + r] * accQ[reg] : 0.f;
      pr += __shfl_xor(pr, 1);
      pr += __shfl_xor(pr, 2);
      pr += __shfl_xor(pr, 4);
      if (r == 0) wv[side][row] = pr;
    }
  }
  __syncthreads();

  // ---- P3b: E = HS .* (A Gm^T) via packed MFMA; z1 partials ----
  {
    const int side = t >> 8, sub = (t >> 6) & 3;
    // A-frag k-slots [Ah|Ah|Al|0], B-frag [Gh|Gl|Gh|0] -> AhGh+AhGl+AlGh
    const int rowA = 16 * sub + r;
    const u16* ap = (g < 2)  ? &sAh[side][rowA][0]
                  : (g == 2) ? &sAl[side][rowA][0] : szero16;
    const bf16x8 af = *(const bf16x8*)ap;
    #pragma unroll
    for (int cb = 0; cb < 4; ++cb) {
      const int rowB = 16 * cb + r;
      const u16* bp = (g == 0) ? &sGh[side][rowB][0]
                    : (g == 1) ? &sGl[side][rowB][0]
                    : (g == 2) ? &sGh[side][rowB][0] : szero16;
      const bf16x8 bf = *(const bf16x8*)bp;
      f32x4 acc = {0.f, 0.f, 0.f, 0.f};
      acc = __builtin_amdgcn_mfma_f32_16x16x32_bf16(af, bf, acc, 0, 0, 0);
      #pragma unroll
      for (int reg = 0; reg < 4; ++reg) {
        const int row = 16 * sub + 4 * g + reg;       // wave-local rows
        const int col = 16 * cb + r;
        const float e = acc[reg] * HS[row * 64 + col];   // L2-hot global
        sE[side][row * 64 + (col ^ ((row & 7) << 3))] = f2bf(e);
      }
    }
    const float wvl = wv[side][l];
    float part = 0.f;
    #pragma unroll
    for (int j = 0; j < 16; ++j) {
      const int kk = 16 * sub + j;
      part += __shfl(wvl, kk) * UG[kk * 64 + l];         // exact fp32, L2-hot
    }
    zp1[side][sub][l] = part;
  }
  // NO barrier: P4's E rows [16sub,16sub+16) were written by this same wave;
  // wave-local LDS write->read ordering is enforced via lgkmcnt (r11-validated).

  // ---- P4: F = E UG^T (MFMA hi-only); fuse z2 ----
  {
    const int side = t >> 8, sub = (t >> 6) & 3;
    f32x4 acc[4];
    #pragma unroll
    for (int nt = 0; nt < 4; ++nt) acc[nt] = (f32x4){0.f, 0.f, 0.f, 0.f};
    #pragma unroll
    for (int ks = 0; ks < 2; ++ks) {
      const int kcol = g * 8 + ks * 32;
      const int rowA = 16 * sub + r;
      const bf16x8 ah = *(const bf16x8*)&sE[side][rowA * 64 + (kcol ^ ((rowA & 7) << 3))];
      #pragma unroll
      for (int nt = 0; nt < 4; ++nt) {
        const int rowB = 16 * nt + r;
        const bf16x8 bh = *(const bf16x8*)&sUGh[rowB * 64 + (kcol ^ ((rowB & 7) << 3))];
        acc[nt] = __builtin_amdgcn_mfma_f32_16x16x32_bf16(ah, bh, acc[nt], 0, 0, 0);
      }
    }
    #pragma unroll
    for (int nt = 0; nt < 4; ++nt) {
      float zp = 0.f;
      #pragma unroll
      for (int reg = 0; reg < 4; ++reg) {
        const int kS = 16 * sub + 4 * g + reg;
        const int iS = 16 * nt + r;
        zp += bf2f(sUGh[iS * 64 + (kS ^ ((iS & 7) << 3))]) * acc[nt][reg];
      }
      zp += __shfl_xor(zp, 16);
      zp += __shfl_xor(zp, 32);
      if (g == 0) zpart[side][sub][16 * nt + r] = zp;
    }
  }
  __syncthreads();

  // ---- P5: combine + write ----
  if (t < 128) {
    const int side = t >> 6, c = t & 63;
    const float z2 = zpart[side][0][c] + zpart[side][1][c] +
                     zpart[side][2][c] + zpart[side][3][c];
    const float z1 = zp1[side][0][c] + zp1[side][1][c] +
                     zp1[side][2][c] + zp1[side][3][c];
    const int col = c * 32 + iT0 + side;
    out[b * 2048 + col] = h0[col] + z1 + z2;
  }
}

extern "C" void kernel_launch(void* const* d_in, const int* in_sizes, int n_in,
                              void* d_out, int out_size, void* d_ws, size_t ws_size,
                              hipStream_t stream) {
  const float* s   = (const float*)d_in[0];  // (16,2048)
  const float* UG  = (const float*)d_in[1];  // (64,64)
  const float* UPT = (const float*)d_in[2];  // (32,32)
  const float* h0  = (const float*)d_in[3];  // (2048,)
  const float* h1c = (const float*)d_in[4];  // (64,8)
  const float* HS  = (const float*)d_in[5];  // (64,64)
  const float* Hc  = (const float*)d_in[6];  // (8,8)
  float* out = (float*)d_out;

  volterra_one<<<256, 512, 0, stream>>>(s, UG, UPT, h0, h1c, HS, Hc, out);
}

// Round 13
// 12.230 us; speedup vs baseline: 1.1684x; 1.0605x over previous
//
#include <hip/hip_runtime.h>

// GraphVolterraLayer: N_S=64, N_T=32, N_EFF=2048, K_T1=K_T2=8, BATCH=16.
// One kernel, grid 256 = (b, iT-pair), 512 threads (8 waves), 4 barriers.
//
//  P0: stage S^T bf16 hi/lo (swz), UG^T bf16 HI (swz), UG hi (swz), UPT f32;
//      raw side weights
//  P1: T1 = UG^T S (MFMA 2-term: UGT hi-only x S hi/lo) -> T1 bf16 HI LDS;
//      weight fold w' = wR UPT^T (VALU, overlaps) -> bf16 hi/lo packs
//  P3a: {Gm|A} = T1 x GmA-pack (2 MFMA), Q = T1 x Q-pack (2 MFMA);
//       Gm,A -> bf16 hi/lo packs [64][8]; wv = rowreduce(h1c .* Q) via shfl
//  P3b: E = HS .* (A Gm^T) via packed MFMA ([Ah|Ah|Al|0]x[Gh|Gl|Gh|0]);
//       E -> bf16 XOR-swz
//  P4:  (barrier) wave owns iS band: F = E UG^T (8 MFMA), z2 in-wave reduce,
//       z1 = UG^T wv in-wave; write out = h0 + z1 + z2 directly. No P5.
// mfma: D[row][col] = sum_k A[row][k]*B[col][k]; A/B: lane row=l&15,
// k-chunk=(l>>4)*8; D: col=l&15, row=4*(l>>4)+reg (m89; validated r6-r12).

typedef short  bf16x8 __attribute__((ext_vector_type(8)));
typedef float  f32x4  __attribute__((ext_vector_type(4)));
typedef unsigned short u16;

static __device__ __forceinline__ u16 f2bf(float f) {
  unsigned u = __float_as_uint(f);
  u = (u + 0x7fff + ((u >> 16) & 1)) >> 16;    // RNE
  return (u16)u;
}
static __device__ __forceinline__ float bf2f(u16 h) {
  return __uint_as_float(((unsigned)h) << 16);
}
static __device__ __forceinline__ float dot4(f32x4 a, f32x4 b) {
  return a.x * b.x + a.y * b.y + a.z * b.z + a.w * b.w;
}
// [N][32]-u16 chunk-swizzled addr (8-u16 chunks; <=2-way bank alias)
static __device__ __forceinline__ int padr(int row, int col) {
  return row * 32 +
         ((((col >> 3) ^ (row & 3) ^ (((row >> 2) & 1) << 1)) & 3) << 3) +
         (col & 7);
}

__global__ __launch_bounds__(512) void volterra_one(
    const float* __restrict__ s, const float* __restrict__ UG,
    const float* __restrict__ UPT, const float* __restrict__ h0,
    const float* __restrict__ h1c, const float* __restrict__ HS,
    const float* __restrict__ Hc, float* __restrict__ out)
{
  const int b   = blockIdx.x >> 4;
  const int iT0 = (blockIdx.x & 15) << 1;
  const int t   = threadIdx.x;
  const int w   = t >> 6;            // wave 0..7
  const int l   = t & 63;
  const int r   = l & 15;
  const int g   = l >> 4;

  __shared__ __align__(16) u16   sSTh[2048], sSTl[2048];   // S^T [32][64] swz
  __shared__ __align__(16) u16   sUGTh[4096];              // UG^T [64][64] swz hi
  __shared__ __align__(16) u16   sUGh[4096];               // UG [64][64] swz hi
  __shared__ __align__(16) float sUPT[32][36];
  __shared__ __align__(16) float wGmR[2][288], wAR[2][288], wQR[2][288];
  __shared__ __align__(16) u16   sT1h[2048];               // T1 [64][32] swz hi
  __shared__ __align__(16) u16   sWGAh[2][512], sWGAl[2][512]; // {Gm|A} w-packs
  __shared__ __align__(16) u16   sWQh[2][512], sWQl[2][512];   // Q w-pack
  __shared__ __align__(16) u16   sGh[2][64][8], sGl[2][64][8]; // Gm hi/lo
  __shared__ __align__(16) u16   sAh[2][64][8], sAl[2][64][8]; // A  hi/lo
  __shared__ __align__(16) u16   szero16[8];
  __shared__ __align__(16) u16   sE[2][4096];
  __shared__ float wv[2][64];

  // ---- P0: stage ----
  {  // S^T bf16 hi/lo, chunk-XOR swizzled
    const f32x4 v = ((const f32x4*)(s + b * 2048))[t];
    const int rr = t >> 3, c0 = (t & 7) * 4;
    const float arr[4] = {v.x, v.y, v.z, v.w};
    #pragma unroll
    for (int i = 0; i < 4; ++i) {
      const int c = c0 + i;
      const u16 hi = f2bf(arr[i]);
      const int ad = c * 64 + (((rr >> 3) ^ (c & 7)) << 3) + (rr & 7);
      sSTh[ad] = hi;
      sSTl[ad] = f2bf(arr[i] - bf2f(hi));
    }
  }
  #pragma unroll
  for (int it = 0; it < 2; ++it) {   // UG: row-major hi + transposed hi
    const int o4 = t + it * 512;
    const int rr = o4 >> 4, c0 = (o4 & 15) * 4;
    const f32x4 v = ((const f32x4*)UG)[o4];
    const float arr[4] = {v.x, v.y, v.z, v.w};
    short4 h4;
    h4.x = (short)f2bf(v.x); h4.y = (short)f2bf(v.y);
    h4.z = (short)f2bf(v.z); h4.w = (short)f2bf(v.w);
    *(short4*)&sUGh[rr * 64 + (c0 ^ ((rr & 7) << 3))] = h4;
    const u16 ha[4] = {(u16)h4.x, (u16)h4.y, (u16)h4.z, (u16)h4.w};
    #pragma unroll
    for (int i = 0; i < 4; ++i) {
      const int c = c0 + i;
      sUGTh[c * 64 + (((rr >> 3) ^ (c & 7)) << 3) + (rr & 7)] = ha[i];
    }
  }
  if (t < 256) {                     // UPT fp32
    *(f32x4*)&sUPT[t >> 3][(t & 7) * 4] = ((const f32x4*)UPT)[t];
  }
  if (t < 8) szero16[t] = 0;
  {                                  // raw per-side weights (global reads only)
    const int side = t >> 8, p = (t >> 5) & 7, k = t & 31;
    const int iTs = iT0 + side;
    const float m1 = UPT[iTs * 32 + k];
    const float m3 = UPT[k * 32 + iTs];
    const float m2 = UPT[k * 32 + p];
    float uh = 0.f;
    #pragma unroll
    for (int q = 0; q < 8; ++q) uh += UPT[k * 32 + q] * Hc[q * 8 + p];
    wGmR[side][p * 36 + k] = m1 * m2;
    wAR [side][p * 36 + k] = m1 * uh;
    wQR [side][p * 36 + k] = m3 * m2;
  }
  __syncthreads();

  // ---- P1: T1 = UG^T S (2-term, 8 wave-tiles) -> bf16 hi; weight fold ----
  {
    const int band = w >> 1, ct = w & 1;
    const int rowA = 16 * band + r, rowB = ct * 16 + r;
    f32x4 acc = {0.f, 0.f, 0.f, 0.f};
    #pragma unroll
    for (int kc = 0; kc < 2; ++kc) {
      const int ch = kc * 4 + g;
      const int oa = rowA * 64 + ((ch ^ (rowA & 7)) << 3);
      const int ob = rowB * 64 + ((ch ^ (rowB & 7)) << 3);
      const bf16x8 Ah = *(const bf16x8*)&sUGTh[oa];
      const bf16x8 Bh = *(const bf16x8*)&sSTh[ob];
      const bf16x8 Bl = *(const bf16x8*)&sSTl[ob];
      acc = __builtin_amdgcn_mfma_f32_16x16x32_bf16(Ah, Bh, acc, 0, 0, 0);
      acc = __builtin_amdgcn_mfma_f32_16x16x32_bf16(Ah, Bl, acc, 0, 0, 0);
    }
    #pragma unroll
    for (int reg = 0; reg < 4; ++reg) {
      const int row = 16 * band + 4 * g + reg;
      sT1h[padr(row, ct * 16 + r)] = f2bf(acc[reg]);
    }
  }
  {  // w'[p][j] = sum_k UPT[j,k] * wR[p][k]  (VALU, overlaps MFMA) -> packs
    const int side = t >> 8, p = (t >> 5) & 7, j = t & 31;
    float aG = 0.f, aA = 0.f, aQ = 0.f;
    #pragma unroll
    for (int k4 = 0; k4 < 8; ++k4) {
      const f32x4 u  = *(const f32x4*)&sUPT[j][k4 * 4];
      const f32x4 w1 = *(const f32x4*)&wGmR[side][p * 36 + k4 * 4];
      const f32x4 w2 = *(const f32x4*)&wAR [side][p * 36 + k4 * 4];
      const f32x4 w3 = *(const f32x4*)&wQR [side][p * 36 + k4 * 4];
      aG += dot4(u, w1); aA += dot4(u, w2); aQ += dot4(u, w3);
    }
    const int adG = padr(p, j), adA = padr(8 + p, j);
    u16 h;
    h = f2bf(aG); sWGAh[side][adG] = h; sWGAl[side][adG] = f2bf(aG - bf2f(h));
    h = f2bf(aA); sWGAh[side][adA] = h; sWGAl[side][adA] = f2bf(aA - bf2f(h));
    h = f2bf(aQ); sWQh[side][adG]  = h; sWQl[side][adG]  = f2bf(aQ - bf2f(h));
    sWQh[side][adA] = 0; sWQl[side][adA] = 0;
  }
  __syncthreads();

  // ---- P3a: {Gm|A} and Q via MFMA (T1 hi-only); packs + wv reduce ----
  {
    const int side = t >> 8, sub = (t >> 6) & 3;
    const int rowA = 16 * sub + r;
    const bf16x8 Ah = *(const bf16x8*)&sT1h[padr(rowA, g * 8)];
    const int ob = padr(r, g * 8);
    const bf16x8 GAh = *(const bf16x8*)&sWGAh[side][ob];
    const bf16x8 GAl = *(const bf16x8*)&sWGAl[side][ob];
    const bf16x8 Qh  = *(const bf16x8*)&sWQh[side][ob];
    const bf16x8 Ql  = *(const bf16x8*)&sWQl[side][ob];
    f32x4 accGA = {0.f, 0.f, 0.f, 0.f}, accQ = {0.f, 0.f, 0.f, 0.f};
    accGA = __builtin_amdgcn_mfma_f32_16x16x32_bf16(Ah, GAh, accGA, 0, 0, 0);
    accGA = __builtin_amdgcn_mfma_f32_16x16x32_bf16(Ah, GAl, accGA, 0, 0, 0);
    accQ  = __builtin_amdgcn_mfma_f32_16x16x32_bf16(Ah, Qh,  accQ,  0, 0, 0);
    accQ  = __builtin_amdgcn_mfma_f32_16x16x32_bf16(Ah, Ql,  accQ,  0, 0, 0);
    #pragma unroll
    for (int reg = 0; reg < 4; ++reg) {
      const int row = 16 * sub + 4 * g + reg;
      const float v = accGA[reg];
      const u16 h = f2bf(v);
      const u16 lo = f2bf(v - bf2f(h));
      if (r < 8) { sGh[side][row][r] = h;     sGl[side][row][r] = lo; }
      else       { sAh[side][row][r - 8] = h; sAl[side][row][r - 8] = lo; }
      float pr = (r < 8) ? h1c[row * 8 + r] * accQ[reg] : 0.f;
      pr += __shfl_xor(pr, 1);
      pr += __shfl_xor(pr, 2);
      pr += __shfl_xor(pr, 4);
      if (r == 0) wv[side][row] = pr;
    }
  }
  __syncthreads();

  // ---- P3b: E = HS .* (A Gm^T) via packed MFMA -> bf16 swz ----
  {
    const int side = t >> 8, sub = (t >> 6) & 3;
    // A-frag k-slots [Ah|Ah|Al|0], B-frag [Gh|Gl|Gh|0] -> AhGh+AhGl+AlGh
    const int rowA = 16 * sub + r;
    const u16* ap = (g < 2)  ? &sAh[side][rowA][0]
                  : (g == 2) ? &sAl[side][rowA][0] : szero16;
    const bf16x8 af = *(const bf16x8*)ap;
    #pragma unroll
    for (int cb = 0; cb < 4; ++cb) {
      const int rowB = 16 * cb + r;
      const u16* bp = (g == 0) ? &sGh[side][rowB][0]
                    : (g == 1) ? &sGl[side][rowB][0]
                    : (g == 2) ? &sGh[side][rowB][0] : szero16;
      const bf16x8 bf = *(const bf16x8*)bp;
      f32x4 acc = {0.f, 0.f, 0.f, 0.f};
      acc = __builtin_amdgcn_mfma_f32_16x16x32_bf16(af, bf, acc, 0, 0, 0);
      #pragma unroll
      for (int reg = 0; reg < 4; ++reg) {
        const int row = 16 * sub + 4 * g + reg;
        const int col = 16 * cb + r;
        const float e = acc[reg] * HS[row * 64 + col];   // L2-hot global
        sE[side][row * 64 + (col ^ ((row & 7) << 3))] = f2bf(e);
      }
    }
  }
  __syncthreads();

  // ---- P4: wave owns iS band q: F = E UG^T (8 MFMA); z2+z1 in-wave; write ----
  {
    const int side = t >> 8, q = (t >> 6) & 3;
    const int iS = 16 * q + r;
    f32x4 acc[4];
    #pragma unroll
    for (int band = 0; band < 4; ++band) acc[band] = (f32x4){0.f, 0.f, 0.f, 0.f};
    #pragma unroll
    for (int ks = 0; ks < 2; ++ks) {
      const int kcol = g * 8 + ks * 32;
      const int rowB = iS;                              // B = UG[iS][.]
      const bf16x8 bh = *(const bf16x8*)&sUGh[rowB * 64 + (kcol ^ ((rowB & 7) << 3))];
      #pragma unroll
      for (int band = 0; band < 4; ++band) {
        const int rowA = 16 * band + r;                 // A = E[kS][.]
        const bf16x8 ah = *(const bf16x8*)&sE[side][rowA * 64 + (kcol ^ ((rowA & 7) << 3))];
        acc[band] = __builtin_amdgcn_mfma_f32_16x16x32_bf16(ah, bh, acc[band], 0, 0, 0);
      }
    }
    // z2 partial: this lane covers kS = 16*band + 4g + reg, col iS = 16q + r
    float tot = 0.f;
    #pragma unroll
    for (int band = 0; band < 4; ++band) {
      #pragma unroll
      for (int reg = 0; reg < 4; ++reg) {
        const int kS = 16 * band + 4 * g + reg;
        tot += bf2f(sUGh[iS * 64 + (kS ^ ((iS & 7) << 3))]) * acc[band][reg];
      }
    }
    // z1 partial: lane covers kk in [16g, 16g+16), exact fp32 UG from L2
    {
      const float wvl = wv[side][l];
      #pragma unroll
      for (int j = 0; j < 16; ++j) {
        const int kk = 16 * g + j;
        tot += __shfl(wvl, kk) * UG[kk * 64 + iS];
      }
    }
    tot += __shfl_xor(tot, 16);
    tot += __shfl_xor(tot, 32);
    if (g == 0) {
      const int col = iS * 32 + iT0 + side;
      out[b * 2048 + col] = h0[col] + tot;
    }
  }
}

extern "C" void kernel_launch(void* const* d_in, const int* in_sizes, int n_in,
                              void* d_out, int out_size, void* d_ws, size_t ws_size,
                              hipStream_t stream) {
  const float* s   = (const float*)d_in[0];  // (16,2048)
  const float* UG  = (const float*)d_in[1];  // (64,64)
  const float* UPT = (const float*)d_in[2];  // (32,32)
  const float* h0  = (const float*)d_in[3];  // (2048,)
  const float* h1c = (const float*)d_in[4];  // (64,8)
  const float* HS  = (const float*)d_in[5];  // (64,64)
  const float* Hc  = (const float*)d_in[6];  // (8,8)
  float* out = (float*)d_out;

  volterra_one<<<256, 512, 0, stream>>>(s, UG, UPT, h0, h1c, HS, Hc, out);
}